// Round 12
// baseline (2674.165 us; speedup 1.0000x reference)
//
#include <hip/hip_runtime.h>

#define B_ 128
#define T_ 256
#define D_ 512
#define H_ 1024
#define O_ 1024
#define NWG 256   // 2 batch domains x 128 column-octet owners
#define NCOL 32   // per-WG gate columns: 4 gates x 8 h-cols

typedef _Float16 f16;
typedef _Float16 f16x8 __attribute__((ext_vector_type(8)));
typedef float f32x4 __attribute__((ext_vector_type(4)));

// h slot stride: [H/8][B][8] f16 = 131072 elements = 256 KB
#define HSTEP 131072ull

// ---- workspace layout (bytes) ----
#define OFF_XH   0ull
#define SZ_XH    33554432ull              // [T][D/8][B][8] f16
#define OFF_WHPK (OFF_XH + SZ_XH)
#define SZ_WHPK  8388608ull               // [128][H/8][NCOL][8] f16
#define OFF_WXPK (OFF_WHPK + SZ_WHPK)
#define SZ_WXPK  4194304ull               // [128][D/8][NCOL][8] f16
#define OFF_BIAS (OFF_WXPK + SZ_WXPK)
#define SZ_BIAS  16384ull                 // [128][NCOL] f32
#define OFF_H    (OFF_BIAS + SZ_BIAS)
#define SZ_H     (2ull * HSTEP * (T_ + 1)) // [T+1][H/8][B][8] f16, WRITE-ONCE rotating
#define OFF_WHPT (OFF_H + SZ_H)
#define SZ_WHPT  4194304ull               // [H][O] f32 (Whp transposed)
#define OFF_BAR  (OFF_WHPT + SZ_WHPT)     // per-(WG,rg) flag array (1024 ints)

// coherent 2B write-through store (L1/L2-bypass -> lands at IC).
// R6 proved scattered 2B sc0sc1 stores are TIME-neutral (only WRITE_SIZE
// sector amplification, invisible in dur).
__device__ __forceinline__ void st_h2(f16* p, unsigned int v)
{
    asm volatile("global_store_short %0, %1, off sc0 sc1"
                 :: "v"(p), "v"(v) : "memory");
}

// coherent flag read on the full-rate VMEM path (NOT the TCC atomic pipe).
__device__ __forceinline__ int ld_flag(const int* p)
{
    int r;
    asm volatile("global_load_dword %0, %1, off sc0 sc1\n\t"
                 "s_waitcnt vmcnt(0)"
                 : "=v"(r) : "v"(p) : "memory");
    return r;
}

// ---------------- prep kernels ----------------

// x[b][t][d] fp32 -> xh[t][d/8][b][8] f16
__global__ __launch_bounds__(256, 1)
void pack_x(const float* __restrict__ x, f16* __restrict__ xh)
{
    const int id = blockIdx.x * 256 + threadIdx.x;
    const int doct = id & 63;
    const int t = (id >> 6) & 255;
    const int b = id >> 14;
    const float* src = x + ((size_t)b * T_ + t) * D_ + (doct << 3);
    const float4 v0 = *(const float4*)src;
    const float4 v1 = *(const float4*)(src + 4);
    f16x8 o;
    o[0] = (f16)v0.x; o[1] = (f16)v0.y; o[2] = (f16)v0.z; o[3] = (f16)v0.w;
    o[4] = (f16)v1.x; o[5] = (f16)v1.y; o[6] = (f16)v1.z; o[7] = (f16)v1.w;
    *(f16x8*)(xh + ((((size_t)t << 6) + doct) * B_ + b) * 8) = o;
}

// Wh[g][o][k] fp32 -> whpk[wc][koct][n][8] f16, n = g*8 + (o - 8wc)
__global__ __launch_bounds__(256, 1)
void pack_wh(const float* __restrict__ Wh, f16* __restrict__ whpk)
{
    const int id = blockIdx.x * 256 + threadIdx.x;
    const int n = id & 31;
    const int koct = (id >> 5) & 127;
    const int w = id >> 12;
    const int g = n >> 3;
    const int o = (w << 3) + (n & 7);
    const float* src = Wh + ((size_t)g * H_ + o) * H_ + (koct << 3);
    const float4 v0 = *(const float4*)src;
    const float4 v1 = *(const float4*)(src + 4);
    f16x8 ov;
    ov[0] = (f16)v0.x; ov[1] = (f16)v0.y; ov[2] = (f16)v0.z; ov[3] = (f16)v0.w;
    ov[4] = (f16)v1.x; ov[5] = (f16)v1.y; ov[6] = (f16)v1.z; ov[7] = (f16)v1.w;
    *(f16x8*)(whpk + (size_t)id * 8) = ov;
}

// Wx[g][o][d] fp32 -> wxpk[wc][doct][n][8] f16
__global__ __launch_bounds__(256, 1)
void pack_wx(const float* __restrict__ Wx, f16* __restrict__ wxpk)
{
    const int id = blockIdx.x * 256 + threadIdx.x;
    const int n = id & 31;
    const int doct = (id >> 5) & 63;
    const int w = id >> 11;
    const int g = n >> 3;
    const int o = (w << 3) + (n & 7);
    const float* src = Wx + ((size_t)g * H_ + o) * D_ + (doct << 3);
    const float4 v0 = *(const float4*)src;
    const float4 v1 = *(const float4*)(src + 4);
    f16x8 ov;
    ov[0] = (f16)v0.x; ov[1] = (f16)v0.y; ov[2] = (f16)v0.z; ov[3] = (f16)v0.w;
    ov[4] = (f16)v1.x; ov[5] = (f16)v1.y; ov[6] = (f16)v1.z; ov[7] = (f16)v1.w;
    *(f16x8*)(wxpk + (size_t)id * 8) = ov;
}

// b[g][o] fp32 -> biasp[wc][n] fp32
__global__ __launch_bounds__(256, 1)
void pack_bias(const float* __restrict__ bsrc, float* __restrict__ biasp)
{
    const int id = blockIdx.x * 256 + threadIdx.x;
    const int n = id & 31;
    const int w = id >> 5;
    biasp[id] = bsrc[((size_t)(n >> 3) << 10) + (w << 3) + (n & 7)];
}

// Whp[o][k] fp32 -> whpT[k][o] fp32
__global__ __launch_bounds__(256, 1)
void whp_t(const float* __restrict__ Whp, float* __restrict__ wT)
{
    __shared__ float tile[64][65];
    const int bx = blockIdx.x & 15;
    const int by = blockIdx.x >> 4;
    for (int i = threadIdx.x; i < 4096; i += 256) {
        const int r = i >> 6, c = i & 63;
        tile[r][c] = Whp[((size_t)(by * 64 + r) << 10) + bx * 64 + c];
    }
    __syncthreads();
    for (int i = threadIdx.x; i < 4096; i += 256) {
        const int r = i >> 6, c = i & 63;
        wT[((size_t)(bx * 64 + r) << 10) + by * 64 + c] = tile[c][r];
    }
}

// ---------------- persistent recurrent kernel ----------------
// 256 WGs x 1024 threads (16 waves/CU).  WG (dom, wc): batch domain dom
// (64 rows) x column octet wc.  Wave (kq 0..3, rg 0..3) computes the
// K-quarter partial for its 16-row group.
// R12 changes vs R11:
//  (a) DIRECT PER-RG PUBLISH: each kq=3 wave stores its own gate outputs
//      (2 x 2B sc0sc1 per lane -- R6 proved time-neutral), drains, and
//      publishes flag[(dom,wc,rg)].  No lds_hst, no wave-0 handoff.
//      Consumer wave (kq,rg) polls flags (wc' in [32kq,32kq+32), ITS rg) --
//      gated only on the 16 rows it actually reads.
//  (b) barrier2 only frees lds_red: kq3 sums between barriers, then does
//      gates+stores+flag AFTER barrier2 with nobody waiting behind it.
//  (c) x-load software pipeline: XA(t+1) issued right after x-MFMAs(t),
//      hiding x-load latency under the wait + h-GEMM.
// h: write-once rotating buffer -> plain cacheable reads (first reader per
// XCD fills L2, others hit; zero fences).
__global__ __launch_bounds__(1024, 1)
void lstm_loop(const f16* __restrict__ xh,
               const f16* __restrict__ whpk,
               const f16* __restrict__ wxpk,
               const float* __restrict__ biasp,
               f16* __restrict__ hbuf,
               int* __restrict__ bar)
{
    __shared__ f16   lds_wh[(H_/8) * NCOL * 8];  // 64 KB
    __shared__ f16   lds_wx[(D_/8) * NCOL * 8];  // 32 KB
    __shared__ float lds_red[3][4][8][64];       // 24 KB, lane-major: conflict-free

    const int tid = threadIdx.x;
    const int w = blockIdx.x;
    const int dom = w >> 7;           // batch domain: rows [64*dom, 64*dom+64)
    const int wc = w & 127;           // column-octet owner

    {   // stage this column-owner's weight slices into LDS (once)
        const f16x8* s1 = (const f16x8*)(whpk + (size_t)wc * (H_/8) * NCOL * 8);
        f16x8* d1 = (f16x8*)lds_wh;
        for (int i = tid; i < (H_/8) * NCOL; i += 1024) d1[i] = s1[i];
        const f16x8* s2 = (const f16x8*)(wxpk + (size_t)wc * (D_/8) * NCOL * 8);
        f16x8* d2 = (f16x8*)lds_wx;
        for (int i = tid; i < (D_/8) * NCOL; i += 1024) d2[i] = s2[i];
    }
    __syncthreads();

    const int lane = tid & 63;
    const int wv = tid >> 6;
    const int kq = wv >> 2;           // K-quarter owner (0..3)
    const int rg = wv & 3;            // row group (16 rows) within the domain
    const int quad = lane >> 4;
    const int l16 = lane & 15;
    const int mrow = (dom << 6) + (rg << 4) + l16;   // global batch row
    const int last = (kq == 3);

    // bias (consumed by kq=3 only; folded into acc init)
    const float b0r = biasp[wc * NCOL + l16];
    const float b1r = biasp[wc * NCOL + 16 + l16];
    const float i0 = last ? b0r : 0.f;
    const float i1 = last ? b1r : 0.f;

    float cs0 = 0.f, cs1 = 0.f;       // cell state (kq=3 waves)
    const int hi = (l16 >> 3) & 1;
    const int r0 = hi << 1;
    const int oc = l16 & 7;
    const int rowbase = (rg << 4) + (quad << 2) + r0;   // local row 0..63

    // my 32 producer flags: (dom, wc' in [32kq, 32kq+32), MY rg)
    const int* __restrict__ fq =
        bar + (dom << 9) + (((kq << 5) + (lane & 31)) << 2) + rg;
    // my publish flag (kq=3 waves): (dom, wc, rg)
    int* __restrict__ fpub = bar + (dom << 9) + (wc << 2) + rg;

    // ---- x-load software pipeline: preload XA for t = 0 ----
    f16x8 XA[4];
    #pragma unroll
    for (int kc = 0; kc < 4; ++kc) {
        const int doct = (kq << 4) + (kc << 2) + quad;
        XA[kc] = *(const f16x8*)(xh + (((size_t)doct << 7) + mrow) * 8);
    }

    for (int t = 0; t < T_; ++t) {
        const f16* __restrict__ hr = hbuf + (size_t)t * HSTEP;
        f16* hw = hbuf + (size_t)(t + 1) * HSTEP;

        f32x4 acc0 = {i0, i0, i0, i0};
        f32x4 acc1 = {i1, i1, i1, i1};

        // ---- x-GEMM partial from preloaded XA ----
        #pragma unroll
        for (int kc = 0; kc < 4; ++kc) {
            const int doct = (kq << 4) + (kc << 2) + quad;
            f16x8 b0 = *(const f16x8*)(lds_wx + ((doct << 5) + l16) * 8);
            f16x8 b1 = *(const f16x8*)(lds_wx + ((doct << 5) + 16 + l16) * 8);
            acc0 = __builtin_amdgcn_mfma_f32_16x16x32_f16(XA[kc], b0, acc0, 0, 0, 0);
            acc1 = __builtin_amdgcn_mfma_f32_16x16x32_f16(XA[kc], b1, acc1, 0, 0, 0);
        }

        // ---- issue XA loads for t+1 (latency hides under wait + h-GEMM) ----
        if (t + 1 < T_) {
            const f16* __restrict__ xtn = xh + (size_t)(t + 1) * (D_/8) * B_ * 8;
            #pragma unroll
            for (int kc = 0; kc < 4; ++kc) {
                const int doct = (kq << 4) + (kc << 2) + quad;
                XA[kc] = *(const f16x8*)(xtn + (((size_t)doct << 7) + mrow) * 8);
            }
        }

        // ---- wait on MY 32 producers (rg-exact) ----
        if (t) {
            while (!__all(ld_flag(fq) >= t))
                __builtin_amdgcn_s_sleep(1);
        }

        // ---- h-GEMM partial (my K-quarter, K=256): 8 loads deep, compute ----
        {
            f16x8 A[8];
            #pragma unroll
            for (int kc = 0; kc < 8; ++kc) {
                const int koct = (kq << 5) + (kc << 2) + quad;
                A[kc] = *(const f16x8*)(hr + (((size_t)koct << 7) + mrow) * 8);
            }
            #pragma unroll
            for (int kc = 0; kc < 8; ++kc) {
                const int koct = (kq << 5) + (kc << 2) + quad;
                f16x8 b0 = *(const f16x8*)(lds_wh + ((koct << 5) + l16) * 8);
                f16x8 b1 = *(const f16x8*)(lds_wh + ((koct << 5) + 16 + l16) * 8);
                acc0 = __builtin_amdgcn_mfma_f32_16x16x32_f16(A[kc], b0, acc0, 0, 0, 0);
                acc1 = __builtin_amdgcn_mfma_f32_16x16x32_f16(A[kc], b1, acc1, 0, 0, 0);
            }
        }

        // ---- K-reduction: kq 0..2 publish partials to LDS ----
        if (!last) {
            #pragma unroll
            for (int r = 0; r < 4; ++r) {
                lds_red[kq][rg][r][lane]     = acc0[r];
                lds_red[kq][rg][4 + r][lane] = acc1[r];
            }
        }
        __syncthreads();

        if (last) {
            #pragma unroll
            for (int q = 0; q < 3; ++q) {
                #pragma unroll
                for (int r = 0; r < 4; ++r) {
                    acc0[r] += lds_red[q][rg][r][lane];
                    acc1[r] += lds_red[q][rg][4 + r][lane];
                }
            }
        }
        __syncthreads();   // lds_red free for t+1; nobody waits behind kq3's tail

        // ---- kq=3 tail: gates + direct 2B publish + per-rg flag ----
        if (last) {
            f32x4 p0, p1;
            #pragma unroll
            for (int r = 0; r < 4; ++r) {
                p0[r] = __shfl_xor(acc0[r], 8, 64);
                p1[r] = __shfl_xor(acc1[r], 8, 64);
            }
            #pragma unroll
            for (int i = 0; i < 2; ++i) {
                const int r = r0 + i;
                const float gi = hi ? p0[r]   : acc0[r];
                const float gf = hi ? acc0[r] : p0[r];
                const float gg = hi ? p1[r]   : acc1[r];
                const float go = hi ? acc1[r] : p1[r];
                const float it = 1.0f / (1.0f + __expf(-gi));
                const float ft = 1.0f / (1.0f + __expf(-gf));
                const float eg = __expf(2.0f * gg);
                const float gt = 1.0f - 2.0f / (eg + 1.0f);   // tanh, inf-safe
                const float ot = 1.0f / (1.0f + __expf(-go));
                float c = (i == 0) ? cs0 : cs1;
                c = ft * c + it * gt;
                if (i == 0) cs0 = c; else cs1 = c;
                const float ec = __expf(2.0f * c);
                const float tc = 1.0f - 2.0f / (ec + 1.0f);   // tanh(c), inf-safe
                union { f16 h; unsigned short u; } cv;
                cv.h = (f16)(ot * tc);
                st_h2(hw + ((size_t)(wc << 7) + (dom << 6) + rowbase + i) * 8 + oc,
                      (unsigned int)cv.u);
            }
            // drain own stores to IC, then publish this rg's flag
            asm volatile("s_waitcnt vmcnt(0)" ::: "memory");
            if (lane == 0)
                __hip_atomic_store(fpub, t + 1, __ATOMIC_RELAXED, __HIP_MEMORY_SCOPE_AGENT);
        }
    }
}

// ---------------- finale: logits = h_T @ Whp^T + bhp; softmax ----------------
__global__ __launch_bounds__(256, 1)
void finale(const f16* __restrict__ hT,
            const float* __restrict__ whpT,
            const float* __restrict__ bhp,
            float* __restrict__ outp)
{
    __shared__ float hrow[H_];
    __shared__ float red[16];
    const int tid = threadIdx.x;
    const int b = blockIdx.x;

    if (tid < H_/8) {
        f16x8 v = *(const f16x8*)(hT + (((size_t)tid << 7) + b) * 8);
        #pragma unroll
        for (int j = 0; j < 8; ++j) hrow[(tid << 3) + j] = (float)v[j];
    }
    __syncthreads();

    float lg0 = bhp[tid], lg1 = bhp[tid + 256], lg2 = bhp[tid + 512], lg3 = bhp[tid + 768];
    for (int k = 0; k < H_; ++k) {
        const float hv = hrow[k];
        const float* wr = whpT + ((size_t)k << 10);
        lg0 = fmaf(hv, wr[tid],       lg0);
        lg1 = fmaf(hv, wr[tid + 256], lg1);
        lg2 = fmaf(hv, wr[tid + 512], lg2);
        lg3 = fmaf(hv, wr[tid + 768], lg3);
    }

    const int lane = tid & 63, wv = tid >> 6;
    float mx = fmaxf(fmaxf(lg0, lg1), fmaxf(lg2, lg3));
    for (int off = 32; off > 0; off >>= 1) mx = fmaxf(mx, __shfl_down(mx, off, 64));
    if (lane == 0) red[wv] = mx;
    __syncthreads();
    mx = fmaxf(fmaxf(red[0], red[1]), fmaxf(red[2], red[3]));

    const float e0 = __expf(lg0 - mx), e1 = __expf(lg1 - mx);
    const float e2 = __expf(lg2 - mx), e3 = __expf(lg3 - mx);
    float s = e0 + e1 + e2 + e3;
    for (int off = 32; off > 0; off >>= 1) s += __shfl_down(s, off, 64);
    if (lane == 0) red[8 + wv] = s;
    __syncthreads();
    s = red[8] + red[9] + red[10] + red[11];
    const float inv = 1.0f / s;

    float* op = outp + ((size_t)b << 10);
    op[tid]       = e0 * inv;
    op[tid + 256] = e1 * inv;
    op[tid + 512] = e2 * inv;
    op[tid + 768] = e3 * inv;
}

// ---------------- launch ----------------
extern "C" void kernel_launch(void* const* d_in, const int* in_sizes, int n_in,
                              void* d_out, int out_size, void* d_ws, size_t ws_size,
                              hipStream_t stream)
{
    const float* x    = (const float*)d_in[0];
    const float* Wx   = (const float*)d_in[1];
    const float* Wh   = (const float*)d_in[2];
    const float* bias = (const float*)d_in[3];
    const float* Whp  = (const float*)d_in[4];
    const float* bhp  = (const float*)d_in[5];

    char* ws = (char*)d_ws;
    f16*   xh    = (f16*)(ws + OFF_XH);
    f16*   whpk  = (f16*)(ws + OFF_WHPK);
    f16*   wxpk  = (f16*)(ws + OFF_WXPK);
    float* biasp = (float*)(ws + OFF_BIAS);
    f16*   hbuf  = (f16*)(ws + OFF_H);
    float* whpT  = (float*)(ws + OFF_WHPT);
    int*   bar   = (int*)(ws + OFF_BAR);

    hipMemsetAsync(ws + OFF_H, 0, 2ull * HSTEP, stream);  // h slot 0 = 0
    hipMemsetAsync(ws + OFF_BAR, 0, 4096, stream);        // flag array (1024 ints) = 0

    pack_x   <<<8192, 256, 0, stream>>>(x, xh);
    pack_wh  <<<2048, 256, 0, stream>>>(Wh, whpk);
    pack_wx  <<<1024, 256, 0, stream>>>(Wx, wxpk);
    pack_bias<<<16,   256, 0, stream>>>(bias, biasp);
    whp_t    <<<256,  256, 0, stream>>>(Whp, whpT);

    lstm_loop<<<NWG, 1024, 0, stream>>>(xh, whpk, wxpk, biasp, hbuf, bar);
    finale   <<<B_,  256, 0, stream>>>(hbuf + (size_t)T_ * HSTEP, whpT, bhp, (float*)d_out);
}

// Round 13
// 1177.775 us; speedup vs baseline: 2.2705x; 2.2705x over previous
//
#include <hip/hip_runtime.h>

#define B_ 128
#define T_ 256
#define D_ 512
#define H_ 1024
#define O_ 1024
#define NWG 256   // 2 batch domains x 128 column-octet owners
#define NCOL 32   // per-WG gate columns: 4 gates x 8 h-cols

typedef _Float16 f16;
typedef _Float16 f16x8 __attribute__((ext_vector_type(8)));
typedef float f32x4 __attribute__((ext_vector_type(4)));

// h slot stride: [H/8][B][8] f16 = 131072 elements = 256 KB
#define HSTEP 131072ull

// ---- workspace layout (bytes) ---- (identical budget to the proven R5/R6 layout)
#define OFF_XH   0ull
#define SZ_XH    33554432ull              // [T][D/8][B][8] f16
#define OFF_WHPK (OFF_XH + SZ_XH)
#define SZ_WHPK  8388608ull               // [128][H/8][NCOL][8] f16
#define OFF_WXPK (OFF_WHPK + SZ_WHPK)
#define SZ_WXPK  4194304ull               // [128][D/8][NCOL][8] f16
#define OFF_BIAS (OFF_WXPK + SZ_WXPK)
#define SZ_BIAS  16384ull                 // [128][NCOL] f32
#define OFF_H    (OFF_BIAS + SZ_BIAS)
#define SZ_H     (2ull * HSTEP * (T_ + 1)) // [T+1][H/8][B][8] f16, WRITE-ONCE rotating
#define OFF_WHPT (OFF_H + SZ_H)
#define SZ_WHPT  4194304ull               // [H][O] f32 (Whp transposed)
#define OFF_BAR  (OFF_WHPT + SZ_WHPT)     // per-WG flag array (NWG ints)

// coherent 16B write-through store (L1/L2-bypass -> lands at IC).
__device__ __forceinline__ void st_h16(f16* p, f16x8 v)
{
    asm volatile("global_store_dwordx4 %0, %1, off sc0 sc1"
                 :: "v"(p), "v"(v) : "memory");
}

// coherent flag read on the full-rate VMEM path (NOT the TCC atomic pipe).
__device__ __forceinline__ int ld_flag(const int* p)
{
    int r;
    asm volatile("global_load_dword %0, %1, off sc0 sc1\n\t"
                 "s_waitcnt vmcnt(0)"
                 : "=v"(r) : "v"(p) : "memory");
    return r;
}

// ---------------- prep kernels ----------------

// x[b][t][d] fp32 -> xh[t][d/8][b][8] f16
__global__ __launch_bounds__(256, 1)
void pack_x(const float* __restrict__ x, f16* __restrict__ xh)
{
    const int id = blockIdx.x * 256 + threadIdx.x;
    const int doct = id & 63;
    const int t = (id >> 6) & 255;
    const int b = id >> 14;
    const float* src = x + ((size_t)b * T_ + t) * D_ + (doct << 3);
    const float4 v0 = *(const float4*)src;
    const float4 v1 = *(const float4*)(src + 4);
    f16x8 o;
    o[0] = (f16)v0.x; o[1] = (f16)v0.y; o[2] = (f16)v0.z; o[3] = (f16)v0.w;
    o[4] = (f16)v1.x; o[5] = (f16)v1.y; o[6] = (f16)v1.z; o[7] = (f16)v1.w;
    *(f16x8*)(xh + ((((size_t)t << 6) + doct) * B_ + b) * 8) = o;
}

// Wh[g][o][k] fp32 -> whpk[wc][koct][n][8] f16, n = g*8 + (o - 8wc)
__global__ __launch_bounds__(256, 1)
void pack_wh(const float* __restrict__ Wh, f16* __restrict__ whpk)
{
    const int id = blockIdx.x * 256 + threadIdx.x;
    const int n = id & 31;
    const int koct = (id >> 5) & 127;
    const int w = id >> 12;
    const int g = n >> 3;
    const int o = (w << 3) + (n & 7);
    const float* src = Wh + ((size_t)g * H_ + o) * H_ + (koct << 3);
    const float4 v0 = *(const float4*)src;
    const float4 v1 = *(const float4*)(src + 4);
    f16x8 ov;
    ov[0] = (f16)v0.x; ov[1] = (f16)v0.y; ov[2] = (f16)v0.z; ov[3] = (f16)v0.w;
    ov[4] = (f16)v1.x; ov[5] = (f16)v1.y; ov[6] = (f16)v1.z; ov[7] = (f16)v1.w;
    *(f16x8*)(whpk + (size_t)id * 8) = ov;
}

// Wx[g][o][d] fp32 -> wxpk[wc][doct][n][8] f16
__global__ __launch_bounds__(256, 1)
void pack_wx(const float* __restrict__ Wx, f16* __restrict__ wxpk)
{
    const int id = blockIdx.x * 256 + threadIdx.x;
    const int n = id & 31;
    const int doct = (id >> 5) & 63;
    const int w = id >> 11;
    const int g = n >> 3;
    const int o = (w << 3) + (n & 7);
    const float* src = Wx + ((size_t)g * H_ + o) * D_ + (doct << 3);
    const float4 v0 = *(const float4*)src;
    const float4 v1 = *(const float4*)(src + 4);
    f16x8 ov;
    ov[0] = (f16)v0.x; ov[1] = (f16)v0.y; ov[2] = (f16)v0.z; ov[3] = (f16)v0.w;
    ov[4] = (f16)v1.x; ov[5] = (f16)v1.y; ov[6] = (f16)v1.z; ov[7] = (f16)v1.w;
    *(f16x8*)(wxpk + (size_t)id * 8) = ov;
}

// b[g][o] fp32 -> biasp[wc][n] fp32
__global__ __launch_bounds__(256, 1)
void pack_bias(const float* __restrict__ bsrc, float* __restrict__ biasp)
{
    const int id = blockIdx.x * 256 + threadIdx.x;
    const int n = id & 31;
    const int w = id >> 5;
    biasp[id] = bsrc[((size_t)(n >> 3) << 10) + (w << 3) + (n & 7)];
}

// Whp[o][k] fp32 -> whpT[k][o] fp32
__global__ __launch_bounds__(256, 1)
void whp_t(const float* __restrict__ Whp, float* __restrict__ wT)
{
    __shared__ float tile[64][65];
    const int bx = blockIdx.x & 15;
    const int by = blockIdx.x >> 4;
    for (int i = threadIdx.x; i < 4096; i += 256) {
        const int r = i >> 6, c = i & 63;
        tile[r][c] = Whp[((size_t)(by * 64 + r) << 10) + bx * 64 + c];
    }
    __syncthreads();
    for (int i = threadIdx.x; i < 4096; i += 256) {
        const int r = i >> 6, c = i & 63;
        wT[((size_t)(bx * 64 + r) << 10) + by * 64 + c] = tile[c][r];
    }
}

// ---------------- persistent recurrent kernel ----------------
// R11 structure (verified 1052 us) + ONE change: the x-GEMM's B-fragments
// (Wx weights) are LOOP-INVARIANT per wave -> held in 32 VGPRs, loaded once
// from global before the loop.  Deletes 8 of 24 ds_read_b128 per wave per
// step (-33% LDS read traffic, the co-critical pipe) and frees 32 KB LDS.
// Everything else identical to R11:
//  - 256 WGs x 1024 threads (16 waves/CU), WG (dom, wc), wave (kq, rg)
//  - K-quarter split, conflict-free lds_red, kq=3 finishes gates+cell
//  - publish: lds_hst staging, wave 0 stores 64x16B sc0sc1 + drain + flag
//    in-order, no trailing barrier
//  - h: write-once rotating buffer, plain cacheable reads
__global__ __launch_bounds__(1024, 1)
void lstm_loop(const f16* __restrict__ xh,
               const f16* __restrict__ whpk,
               const f16* __restrict__ wxpk,
               const float* __restrict__ biasp,
               f16* __restrict__ hbuf,
               int* __restrict__ bar)
{
    __shared__ f16   lds_wh[(H_/8) * NCOL * 8];  // 64 KB
    __shared__ float lds_red[3][4][8][64];       // 24 KB, lane-major: conflict-free
    __shared__ f16   lds_hst[64 * 8];            // 1 KB publish staging

    const int tid = threadIdx.x;
    const int w = blockIdx.x;
    const int dom = w >> 7;           // batch domain: rows [64*dom, 64*dom+64)
    const int wc = w & 127;           // column-octet owner

    {   // stage Wh slice into LDS (once)
        const f16x8* s1 = (const f16x8*)(whpk + (size_t)wc * (H_/8) * NCOL * 8);
        f16x8* d1 = (f16x8*)lds_wh;
        for (int i = tid; i < (H_/8) * NCOL; i += 1024) d1[i] = s1[i];
    }

    const int lane = tid & 63;
    const int wv = tid >> 6;
    const int kq = wv >> 2;           // K-quarter owner (0..3)
    const int rg = wv & 3;            // row group (16 rows) within the domain
    const int quad = lane >> 4;
    const int l16 = lane & 15;
    const int mrow = (dom << 6) + (rg << 4) + l16;   // global batch row
    const int last = (kq == 3);

    // ---- Wx B-fragments: loop-invariant, load ONCE into registers ----
    f16x8 wxb0[4], wxb1[4];
    {
        const f16* wxs = wxpk + (size_t)wc * (D_/8) * NCOL * 8;
        #pragma unroll
        for (int kc = 0; kc < 4; ++kc) {
            const int doct = (kq << 4) + (kc << 2) + quad;
            wxb0[kc] = *(const f16x8*)(wxs + ((doct << 5) + l16) * 8);
            wxb1[kc] = *(const f16x8*)(wxs + ((doct << 5) + 16 + l16) * 8);
        }
    }
    __syncthreads();   // lds_wh staged

    // bias (consumed by kq=3 only; folded into acc init)
    const float b0r = biasp[wc * NCOL + l16];
    const float b1r = biasp[wc * NCOL + 16 + l16];
    const float i0 = last ? b0r : 0.f;
    const float i1 = last ? b1r : 0.f;

    float cs0 = 0.f, cs1 = 0.f;       // cell state (kq=3 waves)
    const int hi = (l16 >> 3) & 1;
    const int r0 = hi << 1;
    const int oc = l16 & 7;
    const int rowbase = (rg << 4) + (quad << 2) + r0;   // local row 0..63

    // my quarter's 32 producer flags (wc in [32kq, 32kq+32), my domain)
    const int* __restrict__ fq = bar + (dom << 7) + (kq << 5) + (lane & 31);

    for (int t = 0; t < T_; ++t) {
        const f16* __restrict__ hr = hbuf + (size_t)t * HSTEP;
        f16* hw = hbuf + (size_t)(t + 1) * HSTEP;

        f32x4 acc0 = {i0, i0, i0, i0};
        f32x4 acc1 = {i1, i1, i1, i1};

        // ---- x-GEMM partial (my D-quarter): 4 loads deep, B from registers ----
        const f16* __restrict__ xt = xh + (size_t)t * (D_/8) * B_ * 8;
        {
            f16x8 XA[4];
            #pragma unroll
            for (int kc = 0; kc < 4; ++kc) {
                const int doct = (kq << 4) + (kc << 2) + quad;
                XA[kc] = *(const f16x8*)(xt + (((size_t)doct << 7) + mrow) * 8);
            }
            #pragma unroll
            for (int kc = 0; kc < 4; ++kc) {
                acc0 = __builtin_amdgcn_mfma_f32_16x16x32_f16(XA[kc], wxb0[kc], acc0, 0, 0, 0);
                acc1 = __builtin_amdgcn_mfma_f32_16x16x32_f16(XA[kc], wxb1[kc], acc1, 0, 0, 0);
            }
        }

        // ---- wait on MY K-quarter's 32 producers ----
        if (t) {
            while (!__all(ld_flag(fq) >= t))
                __builtin_amdgcn_s_sleep(1);
        }

        // ---- h-GEMM partial (my K-quarter, K=256): 8 loads deep, compute ----
        {
            f16x8 A[8];
            #pragma unroll
            for (int kc = 0; kc < 8; ++kc) {
                const int koct = (kq << 5) + (kc << 2) + quad;
                A[kc] = *(const f16x8*)(hr + (((size_t)koct << 7) + mrow) * 8);
            }
            #pragma unroll
            for (int kc = 0; kc < 8; ++kc) {
                const int koct = (kq << 5) + (kc << 2) + quad;
                f16x8 b0 = *(const f16x8*)(lds_wh + ((koct << 5) + l16) * 8);
                f16x8 b1 = *(const f16x8*)(lds_wh + ((koct << 5) + 16 + l16) * 8);
                acc0 = __builtin_amdgcn_mfma_f32_16x16x32_f16(A[kc], b0, acc0, 0, 0, 0);
                acc1 = __builtin_amdgcn_mfma_f32_16x16x32_f16(A[kc], b1, acc1, 0, 0, 0);
            }
        }

        // ---- K-reduction: kq 0..2 publish partials to LDS, kq=3 sums ----
        if (!last) {
            #pragma unroll
            for (int r = 0; r < 4; ++r) {
                lds_red[kq][rg][r][lane]     = acc0[r];
                lds_red[kq][rg][4 + r][lane] = acc1[r];
            }
        }
        __syncthreads();

        if (last) {
            #pragma unroll
            for (int q = 0; q < 3; ++q) {
                #pragma unroll
                for (int r = 0; r < 4; ++r) {
                    acc0[r] += lds_red[q][rg][r][lane];
                    acc1[r] += lds_red[q][rg][4 + r][lane];
                }
            }
            // in-register gate exchange: lane pair {c, 8+c} swap halves
            f32x4 p0, p1;
            #pragma unroll
            for (int r = 0; r < 4; ++r) {
                p0[r] = __shfl_xor(acc0[r], 8, 64);
                p1[r] = __shfl_xor(acc1[r], 8, 64);
            }
            #pragma unroll
            for (int i = 0; i < 2; ++i) {
                const int r = r0 + i;
                const float gi = hi ? p0[r]   : acc0[r];
                const float gf = hi ? acc0[r] : p0[r];
                const float gg = hi ? p1[r]   : acc1[r];
                const float go = hi ? acc1[r] : p1[r];
                const float it = 1.0f / (1.0f + __expf(-gi));
                const float ft = 1.0f / (1.0f + __expf(-gf));
                const float eg = __expf(2.0f * gg);
                const float gt = 1.0f - 2.0f / (eg + 1.0f);   // tanh, inf-safe
                const float ot = 1.0f / (1.0f + __expf(-go));
                float c = (i == 0) ? cs0 : cs1;
                c = ft * c + it * gt;
                if (i == 0) cs0 = c; else cs1 = c;
                const float ec = __expf(2.0f * c);
                const float tc = 1.0f - 2.0f / (ec + 1.0f);   // tanh(c), inf-safe
                lds_hst[((rowbase + i) << 3) + oc] = (f16)(ot * tc);
            }
        }
        __syncthreads();

        // ---- publish: wave 0 stores 64x16B, drains, flags -- IN-ORDER,
        //      no trailing barrier (waves 1-15 run ahead into t+1) ----
        if (tid < 64) {
            f16x8 v = *(const f16x8*)(lds_hst + (tid << 3));
            st_h16(hw + ((size_t)(wc << 7) + (dom << 6) + tid) * 8, v);
            asm volatile("s_waitcnt vmcnt(0)" ::: "memory");
            if (tid == 0)
                __hip_atomic_store(bar + w, t + 1, __ATOMIC_RELAXED, __HIP_MEMORY_SCOPE_AGENT);
        }
    }
}

// ---------------- finale: logits = h_T @ Whp^T + bhp; softmax ----------------
__global__ __launch_bounds__(256, 1)
void finale(const f16* __restrict__ hT,
            const float* __restrict__ whpT,
            const float* __restrict__ bhp,
            float* __restrict__ outp)
{
    __shared__ float hrow[H_];
    __shared__ float red[16];
    const int tid = threadIdx.x;
    const int b = blockIdx.x;

    if (tid < H_/8) {
        f16x8 v = *(const f16x8*)(hT + (((size_t)tid << 7) + b) * 8);
        #pragma unroll
        for (int j = 0; j < 8; ++j) hrow[(tid << 3) + j] = (float)v[j];
    }
    __syncthreads();

    float lg0 = bhp[tid], lg1 = bhp[tid + 256], lg2 = bhp[tid + 512], lg3 = bhp[tid + 768];
    for (int k = 0; k < H_; ++k) {
        const float hv = hrow[k];
        const float* wr = whpT + ((size_t)k << 10);
        lg0 = fmaf(hv, wr[tid],       lg0);
        lg1 = fmaf(hv, wr[tid + 256], lg1);
        lg2 = fmaf(hv, wr[tid + 512], lg2);
        lg3 = fmaf(hv, wr[tid + 768], lg3);
    }

    const int lane = tid & 63, wv = tid >> 6;
    float mx = fmaxf(fmaxf(lg0, lg1), fmaxf(lg2, lg3));
    for (int off = 32; off > 0; off >>= 1) mx = fmaxf(mx, __shfl_down(mx, off, 64));
    if (lane == 0) red[wv] = mx;
    __syncthreads();
    mx = fmaxf(fmaxf(red[0], red[1]), fmaxf(red[2], red[3]));

    const float e0 = __expf(lg0 - mx), e1 = __expf(lg1 - mx);
    const float e2 = __expf(lg2 - mx), e3 = __expf(lg3 - mx);
    float s = e0 + e1 + e2 + e3;
    for (int off = 32; off > 0; off >>= 1) s += __shfl_down(s, off, 64);
    if (lane == 0) red[8 + wv] = s;
    __syncthreads();
    s = red[8] + red[9] + red[10] + red[11];
    const float inv = 1.0f / s;

    float* op = outp + ((size_t)b << 10);
    op[tid]       = e0 * inv;
    op[tid + 256] = e1 * inv;
    op[tid + 512] = e2 * inv;
    op[tid + 768] = e3 * inv;
}

// ---------------- launch ----------------
extern "C" void kernel_launch(void* const* d_in, const int* in_sizes, int n_in,
                              void* d_out, int out_size, void* d_ws, size_t ws_size,
                              hipStream_t stream)
{
    const float* x    = (const float*)d_in[0];
    const float* Wx   = (const float*)d_in[1];
    const float* Wh   = (const float*)d_in[2];
    const float* bias = (const float*)d_in[3];
    const float* Whp  = (const float*)d_in[4];
    const float* bhp  = (const float*)d_in[5];

    char* ws = (char*)d_ws;
    f16*   xh    = (f16*)(ws + OFF_XH);
    f16*   whpk  = (f16*)(ws + OFF_WHPK);
    f16*   wxpk  = (f16*)(ws + OFF_WXPK);
    float* biasp = (float*)(ws + OFF_BIAS);
    f16*   hbuf  = (f16*)(ws + OFF_H);
    float* whpT  = (float*)(ws + OFF_WHPT);
    int*   bar   = (int*)(ws + OFF_BAR);

    hipMemsetAsync(ws + OFF_H, 0, 2ull * HSTEP, stream);  // h slot 0 = 0
    hipMemsetAsync(ws + OFF_BAR, 0, 1024, stream);        // flag array (256 ints) = 0

    pack_x   <<<8192, 256, 0, stream>>>(x, xh);
    pack_wh  <<<2048, 256, 0, stream>>>(Wh, whpk);
    pack_wx  <<<1024, 256, 0, stream>>>(Wx, wxpk);
    pack_bias<<<16,   256, 0, stream>>>(bias, biasp);
    whp_t    <<<256,  256, 0, stream>>>(Whp, whpT);

    lstm_loop<<<NWG, 1024, 0, stream>>>(xh, whpk, wxpk, biasp, hbuf, bar);
    finale   <<<B_,  256, 0, stream>>>(hbuf + (size_t)T_ * HSTEP, whpT, bhp, (float*)d_out);
}